// Round 2
// baseline (1713.482 us; speedup 1.0000x reference)
//
#include <hip/hip_runtime.h>

#define D 256
#define BM 64
#define TN 256      // codes per tile
#define DSUB 64     // dims per subtile
#define ZPAD 260
#define EPAD 68

// -------- kernel 1: sequential fp32 row sum-of-squares (XLA elemental order) ----
// s = 0; for d: s = fl(s + fl(x_d * x_d))   -- strict, no fma, ascending d
__global__ __launch_bounds__(256) void vq_rownorm(const float* __restrict__ x,
                                                  float* __restrict__ out,
                                                  int rows, float* loss_zero) {
#pragma clang fp contract(off)
    int r = blockIdx.x * blockDim.x + threadIdx.x;
    if (r == 0 && loss_zero) loss_zero[0] = 0.f;
    if (r >= rows) return;
    const float* p = x + (size_t)r * D;
    float s = 0.f;
    for (int d = 0; d < D; ++d) {
        float v = p[d];
        float pr = v * v;   // rounded mul
        s = s + pr;         // rounded add, strict sequential
    }
    out[r] = s;
}

// -------- kernel 2: argmin over codes, emulating XLA fp32 arithmetic --------
// g_k   = ascending-d mul+add chain (Eigen gebp order)
// score = fl( fl(nz + ne_k) - fl(2*g_k) )   -> quantized at ulp(nz~256)
// argmin with first-index tie-break (jnp.argmin semantics)
__global__ __launch_bounds__(256) void vq_argmin(
    const float* __restrict__ z, const float* __restrict__ emb,
    const float* __restrict__ enorm, const float* __restrict__ znorm,
    float* __restrict__ idxf_out, int K) {
#pragma clang fp contract(off)
    __shared__ float zs[BM][ZPAD];
    __shared__ float es[TN][EPAD];
    __shared__ float redv[4][BM];
    __shared__ int   redi[4][BM];

    const int tid = threadIdx.x;
    const int tr = tid & 7;        // row group (8)
    const int tc = tid >> 3;       // code group (32)
    const int lane = tid & 63;
    const int w = tid >> 6;
    const int rowBase = blockIdx.x * BM;

    // stage z tile (64 rows x 256 dims), coalesced
    {
        const float4* zg = (const float4*)(z + (size_t)rowBase * D);
        #pragma unroll
        for (int kk = 0; kk < 16; ++kk) {
            int fidx = tid + kk * 256;
            int row = fidx >> 6, c4 = fidx & 63;
            ((float4*)&zs[row][0])[c4] = zg[row * 64 + c4];
        }
    }

    float nzv[8];
    #pragma unroll
    for (int i = 0; i < 8; ++i) nzv[i] = znorm[rowBase + tr + 8 * i];

    float bv[8];
    int bidx[8];
    #pragma unroll
    for (int i = 0; i < 8; ++i) { bv[i] = 3.4e38f; bidx[i] = 0; }

    const int numTiles = K / TN;
    for (int tile = 0; tile < numTiles; ++tile) {
        const int kBase = tile * TN;
        float en[8];
        #pragma unroll
        for (int j = 0; j < 8; ++j) en[j] = enorm[kBase + tc + 32 * j];

        float acc[8][8];
        #pragma unroll
        for (int i = 0; i < 8; ++i)
            #pragma unroll
            for (int j = 0; j < 8; ++j) acc[i][j] = 0.f;

        for (int dsub = 0; dsub < 4; ++dsub) {
            __syncthreads();   // previous es readers done
            {
                const float* eg = emb + (size_t)kBase * D + dsub * DSUB;
                #pragma unroll
                for (int kk = 0; kk < 16; ++kk) {
                    int fidx = tid + kk * 256;
                    int row = fidx >> 4, c4 = fidx & 15;
                    float4 v = *(const float4*)(eg + (size_t)row * D + c4 * 4);
                    ((float4*)&es[row][0])[c4] = v;
                }
            }
            __syncthreads();

            const int dbase = dsub * 16;
            #pragma unroll 2
            for (int ds = 0; ds < 16; ++ds) {
                float4 zv[8], ev[8];
                #pragma unroll
                for (int i = 0; i < 8; ++i)
                    zv[i] = ((const float4*)&zs[tr + 8 * i][0])[dbase + ds];
                #pragma unroll
                for (int j = 0; j < 8; ++j)
                    ev[j] = ((const float4*)&es[tc + 32 * j][0])[ds];
                #pragma unroll
                for (int i = 0; i < 8; ++i)
                    #pragma unroll
                    for (int j = 0; j < 8; ++j) {
                        // strict mul-then-add chain, ascending d (no fma!)
                        acc[i][j] = acc[i][j] + zv[i].x * ev[j].x;
                        acc[i][j] = acc[i][j] + zv[i].y * ev[j].y;
                        acc[i][j] = acc[i][j] + zv[i].z * ev[j].z;
                        acc[i][j] = acc[i][j] + zv[i].w * ev[j].w;
                    }
            }
        }

        // quantized-score argmin epilogue
        #pragma unroll
        for (int j = 0; j < 8; ++j) {
            int k = kBase + tc + 32 * j;
            #pragma unroll
            for (int i = 0; i < 8; ++i) {
                float A = nzv[i] + en[j];     // fl(nz + ne)
                float t = 2.0f * acc[i][j];   // exact
                float s = A - t;              // fl(A - 2g): the quantizing op
                if (s < bv[i]) { bv[i] = s; bidx[i] = k; }   // tie keeps earlier k
            }
        }
    }

    // reduce across the 32 code-group threads sharing each row
    #pragma unroll
    for (int i = 0; i < 8; ++i) {
        float v = bv[i]; int ix = bidx[i];
        #pragma unroll
        for (int off = 8; off < 64; off <<= 1) {
            float v2 = __shfl_xor(v, off);
            int   i2 = __shfl_xor(ix, off);
            if (v2 < v || (v2 == v && i2 < ix)) { v = v2; ix = i2; }
        }
        if ((lane >> 3) == 0) { redv[w][tr + 8 * i] = v; redi[w][tr + 8 * i] = ix; }
    }
    __syncthreads();
    if (tid < BM) {
        float v = redv[0][tid]; int ix = redi[0][tid];
        #pragma unroll
        for (int ww = 1; ww < 4; ++ww) {
            float v2 = redv[ww][tid]; int i2 = redi[ww][tid];
            if (v2 < v || (v2 == v && i2 < ix)) { v = v2; ix = i2; }
        }
        idxf_out[rowBase + tid] = (float)ix;
    }
}

// -------- kernel 3: gather z_q + loss accumulation --------
__global__ __launch_bounds__(256) void vq_gather(
    const float* __restrict__ z, const float* __restrict__ emb,
    const float* __restrict__ idxf, float* __restrict__ zq,
    float* __restrict__ loss, float scale) {
    const int tid = threadIdx.x;
    const int lane = tid & 63, w = tid >> 6;
    const int rowBase = blockIdx.x * 64;
    float lsum = 0.f;
    for (int t = 0; t < 16; ++t) {
        int gr = rowBase + w * 16 + t;
        int k = (int)idxf[gr];
        float4 e  = ((const float4*)emb)[(size_t)k * 64 + lane];
        float4 zv = ((const float4*)z)[(size_t)gr * 64 + lane];
        ((float4*)zq)[(size_t)gr * 64 + lane] = e;   // straight-through fwd value
        float dx = e.x - zv.x, dy = e.y - zv.y, dz = e.z - zv.z, dw = e.w - zv.w;
        lsum = fmaf(dx, dx, lsum); lsum = fmaf(dy, dy, lsum);
        lsum = fmaf(dz, dz, lsum); lsum = fmaf(dw, dw, lsum);
    }
    #pragma unroll
    for (int off = 32; off; off >>= 1) lsum += __shfl_down(lsum, off);
    __shared__ float ps[4];
    if (lane == 0) ps[w] = lsum;
    __syncthreads();
    if (tid == 0) atomicAdd(loss, (ps[0] + ps[1] + ps[2] + ps[3]) * scale);
}

extern "C" void kernel_launch(void* const* d_in, const int* in_sizes, int n_in,
                              void* d_out, int out_size, void* d_ws, size_t ws_size,
                              hipStream_t stream) {
    const float* z   = (const float*)d_in[0];
    const float* emb = (const float*)d_in[1];
    const int N = in_sizes[0] / D;   // 16384
    const int K = in_sizes[1] / D;   // 8192

    float* out  = (float*)d_out;
    float* zq   = out;
    const size_t Z = (size_t)N * D;  // 4194304
    float* loss = out + Z;
    float* idxf = loss + 1;

    // scratch lives in the zq tail; gather overwrites it afterwards (d_ws unused)
    float* znorm = zq + Z - (size_t)N;              // N floats
    float* enorm = zq + Z - (size_t)N - (size_t)K;  // K floats

    vq_rownorm<<<(N + 255) / 256, 256, 0, stream>>>(z, znorm, N, loss);
    vq_rownorm<<<(K + 255) / 256, 256, 0, stream>>>(emb, enorm, K, loss);
    vq_argmin <<<N / BM, 256, 0, stream>>>(z, emb, enorm, znorm, idxf, K);
    vq_gather <<<N / 64, 256, 0, stream>>>(z, emb, idxf, zq, loss,
                                           1.25f / ((float)N * (float)D));
}